// Round 13
// baseline (190.846 us; speedup 1.0000x reference)
//
#include <hip/hip_runtime.h>

// QuantizedLinear: out[t][o] = sum_k x[t][k] * (w_q[o][k]-128)*scale[o] + bias[o]
// M=16, N=8192, K=8192. Memory-bound on w_q (256 MB int32, read once).
//
// R13 = R12 (64.6us: x via global_load_lds + raw barrier + packed FMA)
// + CROSS-BARRIER w-PREFETCH. R12's residual stall: each chunk's first FMA
// consumed freshly-issued w; in-order vmcnt made that wait drain ALL
// outstanding loads -> full HBM latency (~900cy) exposed per chunk, per
// block. Now chunk c consumes only pA/pB registers prefetched at the top of
// chunk c-1 (a full chunk + barrier of latency hiding); post-barrier issues
// are consumed a chunk later, so operand waits leave 16 loads in flight.
// LDS handoff made SOUND (R12's was accidental): explicit vmcnt(8) before
// each barrier retires STAGE(c+1) (issue order pinned by sched_barrier)
// while keeping the 8 prefetched w-loads in flight.

#define IN_F   8192
#define OUT_F  8192
#define NT     16
#define BLOCK  256
#define W_O    4
#define CH_PER_BLOCK 16          // 4 waves * W_O
#define K_CHUNK 512
#define NCHUNK (IN_F / K_CHUNK)  // 16

typedef float f32x2 __attribute__((ext_vector_type(2)));

__global__ __launch_bounds__(BLOCK, 2)
void qlin_kernel(const float* __restrict__ x,     // [16][8192]
                 const int*   __restrict__ w_q,   // [8192][8192]
                 const float* __restrict__ scale, // [8192]
                 const float* __restrict__ bias,  // [8192]
                 float* __restrict__ out)         // [16][8192]
{
    __shared__ float xs[2][NT][K_CHUNK];          // 64 KB -> 2 blocks/CU

    const int tid  = threadIdx.x;
    const int lane = tid & 63;
    const int wave = tid >> 6;
    const int o_base = blockIdx.x * CH_PER_BLOCK + wave * W_O;

    const int* wrow[W_O];
#pragma unroll
    for (int j = 0; j < W_O; ++j)
        wrow[j] = w_q + (size_t)(o_base + j) * IN_F;   // static-indexed only

    // Stage x chunk c (32 KB) into LDS buf b via global_load_lds (VGPR-free).
#define STAGE(c, b)                                                          \
    {                                                                        \
        _Pragma("unroll")                                                    \
        for (int r = 0; r < 8; ++r) {                                        \
            const int f = r * 4096 + wave * 1024 + lane * 16;                \
            const int t = f >> 11;                                           \
            const char* g = (const char*)x + (size_t)t * 32768 +             \
                            (size_t)(c) * 2048 + (f & 2047);                 \
            char* l = (char*)(&xs[0][0][0]) + (b) * 32768 +                  \
                      r * 4096 + wave * 1024;                                \
            __builtin_amdgcn_global_load_lds(                                \
                (const __attribute__((address_space(1))) void*)g,            \
                (__attribute__((address_space(3))) void*)l, 16, 0, 0);       \
        }                                                                    \
    }

    // Prefetch chunk c's 8 w-vectors (4 rows x 2 k-steps) into named regs.
#define PFLOAD(P, c)                                                         \
    {                                                                        \
        _Pragma("unroll")                                                    \
        for (int q = 0; q < 8; ++q) {                                        \
            const int ks = q >> 2, j = q & 3;                                \
            P[q] = *reinterpret_cast<const int4*>(                           \
                wrow[j] + (c) * K_CHUNK + ks * 256 + lane * 4);              \
        }                                                                    \
    }

    // One 256-wide k-step from prefetched regs + LDS x.
#define KSTEP(P, ks, cur)                                                    \
    {                                                                        \
        const int4 w0 = P[(ks) * 4 + 0], w1 = P[(ks) * 4 + 1];               \
        const int4 w2 = P[(ks) * 4 + 2], w3 = P[(ks) * 4 + 3];               \
        f32x2 wf[2][4];                                                      \
        wf[0][0] = (f32x2){(float)(w0.x - 128), (float)(w1.x - 128)};        \
        wf[0][1] = (f32x2){(float)(w0.y - 128), (float)(w1.y - 128)};        \
        wf[0][2] = (f32x2){(float)(w0.z - 128), (float)(w1.z - 128)};        \
        wf[0][3] = (f32x2){(float)(w0.w - 128), (float)(w1.w - 128)};        \
        wf[1][0] = (f32x2){(float)(w2.x - 128), (float)(w3.x - 128)};        \
        wf[1][1] = (f32x2){(float)(w2.y - 128), (float)(w3.y - 128)};        \
        wf[1][2] = (f32x2){(float)(w2.z - 128), (float)(w3.z - 128)};        \
        wf[1][3] = (f32x2){(float)(w2.w - 128), (float)(w3.w - 128)};        \
        _Pragma("unroll")                                                    \
        for (int t = 0; t < NT; ++t) {                                       \
            const float4 xv = *reinterpret_cast<const float4*>(              \
                &xs[cur][t][(ks) * 256 + lane * 4]);                         \
            acc2[t][0] += wf[0][0] * (f32x2){xv.x, xv.x};                    \
            acc2[t][1] += wf[1][0] * (f32x2){xv.x, xv.x};                    \
            acc2[t][0] += wf[0][1] * (f32x2){xv.y, xv.y};                    \
            acc2[t][1] += wf[1][1] * (f32x2){xv.y, xv.y};                    \
            acc2[t][0] += wf[0][2] * (f32x2){xv.z, xv.z};                    \
            acc2[t][1] += wf[1][2] * (f32x2){xv.z, xv.z};                    \
            acc2[t][0] += wf[0][3] * (f32x2){xv.w, xv.w};                    \
            acc2[t][1] += wf[1][3] * (f32x2){xv.w, xv.w};                    \
        }                                                                    \
    }

    // Chunk body: issue next chunk's stage + w-prefetch (pinned order), then
    // compute from THIS chunk's prefetched regs, then sound LDS handoff:
    // vmcnt(8) retires STAGE(c+1) (8 PF loads stay in flight) before barrier.
#define CHUNK(c, P_CUR, P_NXT)                                               \
    {                                                                        \
        if ((c) + 1 < NCHUNK) {                                              \
            STAGE((c) + 1, ((c) & 1) ^ 1)                                    \
            __builtin_amdgcn_sched_barrier(0);                               \
            PFLOAD(P_NXT, (c) + 1)                                           \
        }                                                                    \
        __builtin_amdgcn_sched_barrier(0);                                   \
        KSTEP(P_CUR, 0, (c) & 1)                                             \
        KSTEP(P_CUR, 1, (c) & 1)                                             \
        __builtin_amdgcn_sched_barrier(0);                                   \
        if ((c) + 1 < NCHUNK) {                                              \
            asm volatile("s_waitcnt vmcnt(8)" ::: "memory");                 \
            __builtin_amdgcn_s_barrier();                                    \
            __builtin_amdgcn_sched_barrier(0);                               \
        }                                                                    \
    }

    f32x2 acc2[NT][2];   // acc2[t][j2][e] = acc[t][j2*2+e]; 64 VGPRs
#pragma unroll
    for (int t = 0; t < NT; ++t) {
        acc2[t][0] = (f32x2)0.0f;
        acc2[t][1] = (f32x2)0.0f;
    }

    int4 pA[8], pB[8];   // double-buffered w prefetch (static indexing only)

    // prologue: stage chunk 0 + prefetch chunk 0; retire stage, keep PF flying
    STAGE(0, 0)
    __builtin_amdgcn_sched_barrier(0);
    PFLOAD(pA, 0)
    __builtin_amdgcn_sched_barrier(0);
    asm volatile("s_waitcnt vmcnt(8)" ::: "memory");
    __builtin_amdgcn_s_barrier();
    __builtin_amdgcn_sched_barrier(0);

#pragma unroll 1
    for (int cc = 0; cc < NCHUNK; cc += 2) {
        CHUNK(cc + 0, pA, pB)
        CHUNK(cc + 1, pB, pA)
    }

#undef STAGE
#undef PFLOAD
#undef KSTEP
#undef CHUNK

    // ---- cross-lane reduction: 64 (t,j) values, 6-step butterfly each ----
    float myval = 0.0f;
#pragma unroll
    for (int t = 0; t < NT; ++t) {
#pragma unroll
        for (int j = 0; j < W_O; ++j) {
            float v = acc2[t][j >> 1][j & 1];
#pragma unroll
            for (int off = 32; off > 0; off >>= 1)
                v += __shfl_xor(v, off, 64);
            if (lane == (t * W_O + j)) myval = v;
        }
    }

    // lane l -> (t = l>>2, channel j = l&3)
    const int t_o = lane >> 2;
    const int o   = o_base + (lane & 3);
    out[(size_t)t_o * OUT_F + o] = myval * scale[o] + bias[o];
}

extern "C" void kernel_launch(void* const* d_in, const int* in_sizes, int n_in,
                              void* d_out, int out_size, void* d_ws, size_t ws_size,
                              hipStream_t stream) {
    const float* x     = (const float*)d_in[0];
    const int*   w_q   = (const int*)d_in[1];
    const float* scale = (const float*)d_in[2];
    const float* bias  = (const float*)d_in[3];
    float*       out   = (float*)d_out;

    dim3 grid(OUT_F / CH_PER_BLOCK);   // 512 blocks -> 2 per CU
    dim3 block(BLOCK);
    qlin_kernel<<<grid, block, 0, stream>>>(x, w_q, scale, bias, out);
}